// Round 7
// baseline (21.190 us; speedup 1.0000x reference)
//
#include <hip/hip_runtime.h>
#include <math.h>

#define B_ 2
#define N_ 512
#define C_ 32
#define H_ 200
#define W_ 200
#define HW_ (H_*W_)
#define THRESH_ 0.05f
#define OUT_BEV (B_*C_*H_*W_)
#define NSEG 8                    // waves per block; each wave owns 64 gaussians
#define TPB 3                     // tiles rendered per block
#define BPB 209                   // blocks per batch = ceil(625/3)
#define TILES_PER_B 625           // 25x25 tiles of 8x8
#define LOG2E 1.4426950408889634f
#define LN2   0.6931471805599453f

typedef float v2f __attribute__((ext_vector_type(2)));

// Blocks 0..417: batch b = blk/209, renders tiles tb*3..tb*3+2 (8 waves,
// ordered 64-gaussian segments, params register-resident across tiles).
// Block 418: num_gaussians scalar.
__global__ __launch_bounds__(512, 4) void render_kernel(
    const float* __restrict__ features,   // [B,N,C]
    const float* __restrict__ means3D,    // [B,N,3]
    const float* __restrict__ cov3D,      // [B,N,6]
    const float* __restrict__ opacities,  // [B,N,1]
    float* __restrict__ out)              // [B,C,H,W] + 1 scalar
{
    __shared__ float s_T[NSEG][64];            // 2 KB
    __shared__ float s_W[NSEG * 64];           // 2 KB
    __shared__ float4 u_mem[NSEG * 16 * 16];   // 32 KB: s_hit (low 16 KB) | s_acc
    float4* s_hit = u_mem;                     // [wave*128 + 2*slot]
    float (*s_acc)[16][64] = (float (*)[16][64])u_mem;   // [8][16][64]

    int blk = blockIdx.x;
    int tid = threadIdx.x;

    if (blk == 2 * BPB) {                      // ---- count-only block ----
        int cnt = ((opacities[tid]       > THRESH_) ? 1 : 0)
                + ((opacities[tid + 512] > THRESH_) ? 1 : 0);
        for (int off = 32; off > 0; off >>= 1) cnt += __shfl_down(cnt, off);
        int* s_red = (int*)s_W;
        if ((tid & 63) == 0) s_red[tid >> 6] = cnt;
        __syncthreads();
        if (tid == 0) {
            int tot = 0;
            for (int g = 0; g < NSEG; ++g) tot += s_red[g];
            out[OUT_BEV] = (float)tot * 0.5f;
        }
        return;
    }

    int b  = blk / BPB;
    int tb = blk - b * BPB;
    int wave = __builtin_amdgcn_readfirstlane(tid >> 6);   // uniform
    int lane = tid & 63;

    // ---- prologue (once per block): lane owns gaussian wave*64+lane ----
    float mu_u, mu_v, a2, b2, c2, opac, thr2, du_max, dv_max;
    {
        int i = b * N_ + wave * 64 + lane;
        float x  = means3D[i*3 + 0];
        float y  = means3D[i*3 + 1];
        float c0 = cov3D[i*6 + 0];
        float c1 = cov3D[i*6 + 1];
        float c3 = cov3D[i*6 + 3];
        float op = opacities[i];
        mu_u = 100.0f - 100.0f * y;
        mu_v = 100.0f - 100.0f * x;
        float Cuu = 10000.0f * c3 + 0.3f;
        float Cvv = 10000.0f * c0 + 0.3f;
        float Cuv = 10000.0f * c1;
        float det = Cuu * Cvv - Cuv * Cuv;
        bool valid = det > 0.0f;
        opac = (op > THRESH_) ? op : 0.0f;
        if (!valid) opac = 0.0f;
        float inv_det = valid ? (1.0f / det) : 0.0f;
        a2 = -0.5f * LOG2E * (Cvv * inv_det);
        b2 = -0.5f * LOG2E * (Cuu * inv_det);
        c2 =  LOG2E * (Cuv * inv_det);
        if (opac > 0.0f) {
            float r2 = log2f(255.0f * opac);       // > 0 since opac > 0.05
            thr2 = -r2;
            float rn = LN2 * r2;
            du_max = sqrtf(fmaxf(2.0f * rn * Cuu, 0.0f)) + 1.0e-3f;
            dv_max = sqrtf(fmaxf(2.0f * rn * Cvv, 0.0f)) + 1.0e-3f;
        } else {
            thr2 = 3.0e38f;
            du_max = -1.0e30f;                     // empty bbox
            dv_max = -1.0e30f;
        }
    }
    const float* featB = features + (size_t)b * (N_ * C_);

    // ---- render TPB tiles with the same register-resident params ----
    for (int s = 0; s < TPB; ++s) {
        int t = tb * TPB + s;
        if (t >= TILES_PER_B) break;               // block-uniform
        int tu = t / 25;
        int tv = t - tu * 25;
        float tu0 = (float)(tu * 8), tu1 = tu0 + 7.0f;
        float tv0 = (float)(tv * 8), tv1 = tv0 + 7.0f;

        // cull + order-preserving compaction into this wave's LDS region
        bool ov = (mu_u - du_max <= tu1) & (mu_u + du_max >= tu0) &
                  (mu_v - dv_max <= tv1) & (mu_v + dv_max >= tv0);
        unsigned long long m = __ballot(ov);
        int pos = __builtin_amdgcn_mbcnt_hi((unsigned)(m >> 32),
                  __builtin_amdgcn_mbcnt_lo((unsigned)m, 0));
        if (ov) {
            int sl = wave * 128 + 2 * pos;
            s_hit[sl]     = make_float4(mu_u, mu_v, a2, b2);
            s_hit[sl + 1] = make_float4(c2, opac, thr2, 0.0f);
        }
        int nh = __builtin_amdgcn_readfirstlane(__popcll(m));

        int uu = tu * 8 + (lane >> 3);
        int vv = tv * 8 + (lane & 7);
        float u = (float)uu, v = (float)vv;

        float T = 1.0f;
        v2f acc2[16];
#pragma unroll
        for (int i = 0; i < 16; ++i) acc2[i] = (v2f){0.0f, 0.0f};

        unsigned long long w = m;
        // counted, branchless hit loop (ascending n == slot order)
#pragma unroll 2
        for (int k = 0; k < nh; ++k) {
            float4 q0 = s_hit[wave * 128 + 2 * k];       // broadcast ds_read
            float4 q1 = s_hit[wave * 128 + 2 * k + 1];
            int j = __builtin_ctzll(w);
            w &= w - 1;
            int n = __builtin_amdgcn_readfirstlane(wave * 64 + j);
            const v2f* f2 = (const v2f*)(featB + (size_t)n * C_);  // s_load
            float du = u - q0.x;
            float dv = v - q0.y;
            float pw = fmaf(q0.z * du, du, fmaf(q0.w * dv, dv, q1.x * (du * dv)));
            bool hit = (pw <= 0.0f) && (pw >= q1.z);
            float al = hit ? fminf(0.99f, q1.y * exp2f(pw)) : 0.0f;
            float wgt = T * al;
            v2f w2 = {wgt, wgt};
#pragma unroll
            for (int i = 0; i < 16; ++i)
                acc2[i] = __builtin_elementwise_fma(w2, f2[i], acc2[i]);
            T *= (1.0f - al);
        }

        // ---- combine: prefix transmittance + 2 channel-rounds through LDS --
        s_T[wave][lane] = T;
        __syncthreads();           // (A) hit loops + previous-tile reads done

        {
            float Wg = 1.0f;
            for (int g = 0; g < wave; ++g) Wg *= s_T[g][lane];
            s_W[wave * 64 + lane] = Wg;
        }

        size_t obase = (size_t)b * C_ * HW_ + (size_t)(tu * 8) * W_ + (size_t)(tv * 8);
        size_t opix  = (size_t)(lane >> 3) * W_ + (lane & 7);
#pragma unroll
        for (int k2 = 0; k2 < 2; ++k2) {
#pragma unroll
            for (int cc = 0; cc < 8; ++cc) {
                v2f a = acc2[k2 * 8 + cc];
                s_acc[wave][cc * 2][lane]     = a.x;
                s_acc[wave][cc * 2 + 1][lane] = a.y;
            }
            __syncthreads();       // (B) s_acc (and s_W on k2==0) visible
            float v0 = 0.0f, v1 = 0.0f;
#pragma unroll
            for (int g = 0; g < NSEG; ++g) {
                float wgt = s_W[g * 64 + lane];
                v0 = fmaf(wgt, s_acc[g][wave * 2][lane],     v0);
                v1 = fmaf(wgt, s_acc[g][wave * 2 + 1][lane], v1);
            }
            out[obase + (size_t)(k2 * 16 + wave * 2) * HW_ + opix]     = v0;
            out[obase + (size_t)(k2 * 16 + wave * 2 + 1) * HW_ + opix] = v1;
            __syncthreads();       // (C) reads done before re-staging / next tile
        }
    }
}

extern "C" void kernel_launch(void* const* d_in, const int* in_sizes, int n_in,
                              void* d_out, int out_size, void* d_ws, size_t ws_size,
                              hipStream_t stream) {
    const float* features  = (const float*)d_in[0];
    const float* means3D   = (const float*)d_in[1];
    const float* cov3D     = (const float*)d_in[2];
    const float* opacities = (const float*)d_in[3];
    float* out = (float*)d_out;
    render_kernel<<<2 * BPB + 1, 512, 0, stream>>>(
        features, means3D, cov3D, opacities, out);
}